// Round 3
// baseline (107.300 us; speedup 1.0000x reference)
//
#include <hip/hip_runtime.h>

// RippleLinear: out[b,o] = sum_i amp[i,o] * sin(x[b,i]*freq[i,o] + ph[i,o]) + bias0[o]
//   x:      (2048, 256) f32   (16*128 rows)
//   weight: (256, 256, 2) f32  -> amp = w[i][o][0], freq = w[i][o][1]
//   bias:   (257, 256) f32     -> bias0 = bias[0][:], ph[i][o] = bias[1+i][o]
//   out:    (2048, 256) f32
//
// R2 -> R3: grid=256 was 1 block/CU -> hard 50% occupancy cap (measured 39%,
// VALUBusy 33%). BTILE 8->4, grid 512 -> 2 blocks/CU = 32 waves/CU. L2 weight
// re-stream 512*768KB = 384 MB ~= 11 us @ 34.5 TB/s, just under the ~12 us
// compute floor (134M v_sin @ quarter rate + ~3 VALU each) -> still hidden.
// __launch_bounds__(1024, 8) pins VGPRs <= 64 so 8 waves/SIMD fit.

constexpr int IN_F   = 256;
constexpr int OUT_F  = 256;
constexpr int BROWS  = 2048;
constexpr int BTILE  = 4;   // batch rows per block
constexpr int ISPLIT = 4;   // i-dimension split inside the block
constexpr int ICHUNK = IN_F / ISPLIT;  // 64 i per group

__global__ __launch_bounds__(OUT_F * ISPLIT, 8) void ripple_kernel(
    const float* __restrict__ x,       // (BROWS, IN_F)
    const float* __restrict__ weight,  // (IN_F, OUT_F, 2)
    const float* __restrict__ bias,    // (IN_F+1, OUT_F)
    float* __restrict__ out)           // (BROWS, OUT_F)
{
    const int o  = threadIdx.x;            // 0..255, output column
    const int g  = threadIdx.y;            // 0..3, i-group
    const int b0 = blockIdx.x * BTILE;     // batch-row base

    float acc[BTILE];
#pragma unroll
    for (int r = 0; r < BTILE; ++r) acc[r] = 0.0f;

    const float2* __restrict__ w2 = (const float2*)weight;  // (amp,freq) pairs

    const int i0 = g * ICHUNK;
#pragma unroll 2
    for (int ii = 0; ii < ICHUNK; ++ii) {
        const int i = i0 + ii;
        const float2 w  = w2[i * OUT_F + o];          // coalesced 8B/lane
        const float  ph = bias[(i + 1) * OUT_F + o];  // coalesced 4B/lane

        // x values are block-uniform -> scalar loads
        float xv[BTILE];
#pragma unroll
        for (int r = 0; r < BTILE; ++r)
            xv[r] = x[(b0 + r) * IN_F + i];

#pragma unroll
        for (int r = 0; r < BTILE; ++r)
            acc[r] += w.x * __sinf(fmaf(xv[r], w.y, ph));
    }

    // cross-group reduction: groups 1..3 park partials in LDS, group 0 sums.
    __shared__ float red[ISPLIT - 1][BTILE][OUT_F];  // 12 KB
    if (g > 0) {
#pragma unroll
        for (int r = 0; r < BTILE; ++r) red[g - 1][r][o] = acc[r];
    }
    __syncthreads();
    if (g == 0) {
        const float bo = bias[o];
#pragma unroll
        for (int r = 0; r < BTILE; ++r) {
            float s = acc[r];
#pragma unroll
            for (int gg = 0; gg < ISPLIT - 1; ++gg) s += red[gg][r][o];
            out[(b0 + r) * OUT_F + o] = s + bo;
        }
    }
}

extern "C" void kernel_launch(void* const* d_in, const int* in_sizes, int n_in,
                              void* d_out, int out_size, void* d_ws, size_t ws_size,
                              hipStream_t stream) {
    const float* x      = (const float*)d_in[0];
    const float* weight = (const float*)d_in[1];
    const float* bias   = (const float*)d_in[2];
    float* out          = (float*)d_out;

    dim3 grid(BROWS / BTILE);        // 512 blocks -> 2 blocks/CU
    dim3 block(OUT_F, ISPLIT);       // 1024 threads
    ripple_kernel<<<grid, block, 0, stream>>>(x, weight, bias, out);
}

// Round 4
// 77.030 us; speedup vs baseline: 1.3930x; 1.3930x over previous
//
#include <hip/hip_runtime.h>

// RippleLinear: out[b,o] = sum_i amp[i,o] * sin(x[b,i]*freq[i,o] + ph[i,o]) + bias0[o]
//   x:      (2048, 256) f32   (16*128 rows)
//   weight: (256, 256, 2) f32  -> amp = w[i][o][0], freq = w[i][o][1]
//   bias:   (257, 256) f32     -> bias0 = bias[0][:], ph[i][o] = bias[1+i][o]
//   out:    (2048, 256) f32
//
// R3 -> R4: R3 (2 blocks/CU via grid 512, BTILE 4) REGRESSED 47->57us:
// doubling grid doubled weight re-stream (201->402 MB) while VALUBusy fell
// 33->29% -- per-wave load-chain latency is the floor, not wave count.
// R4: thread owns an o-PAIR -> one float4 (amp0,freq0,amp1,freq1) + one
// float2 ph per i feeds 16 sins (2 cols x 8 rows): 3x fewer load-stall
// points/sin. x-tile (8KB) staged in LDS once/block, hot-loop reads are
// ds_read broadcasts. OB=2 o-halves x BB=256 row-blocks: grid 512 x 512thr,
// 16 waves/CU, weight traffic back to 201 MB. ISPLIT=8 + 3-step LDS tree.

constexpr int IN_F   = 256;
constexpr int OUT_F  = 256;
constexpr int BROWS  = 2048;
constexpr int BTILE  = 8;                 // batch rows per block (in registers)
constexpr int ISPLIT = 8;                 // i-groups per block (one wave each)
constexpr int ICHUNK = IN_F / ISPLIT;     // 32 i per group
constexpr int OPAIRS = 64;                // o-pairs per block (= 128 o columns)

__global__ __launch_bounds__(OPAIRS * ISPLIT, 4) void ripple_kernel(
    const float* __restrict__ x,       // (BROWS, IN_F)
    const float* __restrict__ weight,  // (IN_F, OUT_F, 2)
    const float* __restrict__ bias,    // (IN_F+1, OUT_F)
    float* __restrict__ out)           // (BROWS, OUT_F)
{
    const int tx = threadIdx.x;           // 0..63: o-pair lane
    const int g  = threadIdx.y;           // 0..7: i-group (one wave)
    const int ob = blockIdx.x & 1;        // which o-half
    const int bb = blockIdx.x >> 1;       // row-block
    const int b0 = bb * BTILE;
    const int oc = ob * OPAIRS + tx;      // global o-pair index 0..127

    __shared__ float  xs[BTILE * IN_F];       // 8 KB x-tile, xs[r*256+i]
    __shared__ float2 red[4][BTILE][OPAIRS];  // 16 KB reduction buffer

    // --- stage x-tile: 2048 floats, 512 threads x float4, coalesced ---
    {
        const int t = g * OPAIRS + tx;    // 0..511
        ((float4*)xs)[t] = ((const float4*)x)[b0 * (IN_F / 4) + t];
    }
    __syncthreads();

    float acc0[BTILE], acc1[BTILE];
#pragma unroll
    for (int r = 0; r < BTILE; ++r) { acc0[r] = 0.0f; acc1[r] = 0.0f; }

    const float4* __restrict__ wq  = (const float4*)weight;  // (amp0,freq0,amp1,freq1)
    const float2* __restrict__ ph2 = (const float2*)bias;    // phase pairs

    const int i0 = g * ICHUNK;
#pragma unroll 2
    for (int ii = 0; ii < ICHUNK; ++ii) {
        const int i = i0 + ii;
        const float4 w = wq[i * (OUT_F / 2) + oc];           // 16B coalesced
        const float2 p = ph2[(i + 1) * (OUT_F / 2) + oc];    // 8B coalesced
#pragma unroll
        for (int r = 0; r < BTILE; ++r) {
            const float xv = xs[r * IN_F + i];               // LDS broadcast
            acc0[r] += w.x * __sinf(fmaf(xv, w.y, p.x));
            acc1[r] += w.z * __sinf(fmaf(xv, w.w, p.y));
        }
    }

    // --- 3-step cross-wave tree reduction over the 8 i-groups ---
    if (g >= 4) {
#pragma unroll
        for (int r = 0; r < BTILE; ++r) red[g - 4][r][tx] = make_float2(acc0[r], acc1[r]);
    }
    __syncthreads();
    if (g < 4) {
#pragma unroll
        for (int r = 0; r < BTILE; ++r) { float2 t = red[g][r][tx]; acc0[r] += t.x; acc1[r] += t.y; }
    }
    __syncthreads();
    if (g == 2 || g == 3) {
#pragma unroll
        for (int r = 0; r < BTILE; ++r) red[g - 2][r][tx] = make_float2(acc0[r], acc1[r]);
    }
    __syncthreads();
    if (g < 2) {
#pragma unroll
        for (int r = 0; r < BTILE; ++r) { float2 t = red[g][r][tx]; acc0[r] += t.x; acc1[r] += t.y; }
    }
    __syncthreads();
    if (g == 1) {
#pragma unroll
        for (int r = 0; r < BTILE; ++r) red[0][r][tx] = make_float2(acc0[r], acc1[r]);
    }
    __syncthreads();
    if (g == 0) {
        const float2 bo = ph2[oc];   // bias row 0, this o-pair
#pragma unroll
        for (int r = 0; r < BTILE; ++r) {
            float2 t = red[0][r][tx];
            float2 v = make_float2(acc0[r] + t.x + bo.x, acc1[r] + t.y + bo.y);
            ((float2*)out)[(b0 + r) * (OUT_F / 2) + oc] = v;
        }
    }
}

extern "C" void kernel_launch(void* const* d_in, const int* in_sizes, int n_in,
                              void* d_out, int out_size, void* d_ws, size_t ws_size,
                              hipStream_t stream) {
    const float* x      = (const float*)d_in[0];
    const float* weight = (const float*)d_in[1];
    const float* bias   = (const float*)d_in[2];
    float* out          = (float*)d_out;

    dim3 grid((BROWS / BTILE) * 2);     // 512 blocks: 256 row-blocks x 2 o-halves
    dim3 block(OPAIRS, ISPLIT);         // 512 threads = 8 waves
    ripple_kernel<<<grid, block, 0, stream>>>(x, weight, bias, out);
}

// Round 5
// 75.262 us; speedup vs baseline: 1.4257x; 1.0235x over previous
//
#include <hip/hip_runtime.h>

// RippleLinear: out[b,o] = sum_i amp[i,o] * sin(x[b,i]*freq[i,o] + ph[i,o]) + bias0[o]
//   x:      (2048, 256) f32   (16*128 rows)
//   weight: (256, 256, 2) f32  -> amp = w[i][o][0], freq = w[i][o][1]
//   bias:   (257, 256) f32     -> bias0 = bias[0][:], ph[i][o] = bias[1+i][o]
//   out:    (2048, 256) f32
//
// R4 -> R5 (R4 kernel ~26us; floor ~10us). Three traffic-neutral fixes:
//  1. x-tile TRANSPOSED in LDS (xs_t[i*8+r]) -> 2x ds_read_b128 broadcast
//     per iter instead of 8x ds_read_b32 (LDS pipe 9.8 -> ~5 us/CU).
//  2. sin(x*f+p) = v_sin((x/2pi)*f + p/2pi): prescale x at staging (free),
//     scale phase once per iter (amortized over 16 sins), call raw
//     __builtin_amdgcn_sinf -> 2 full-rate VALU/sin instead of 3.
//  3. unroll 4 for deeper weight-stream load-ahead.
// Structure unchanged: grid 512 = 256 row-blocks x 2 o-halves, block (64,8),
// thread owns an o-pair, ISPLIT=8 + 3-step LDS tree reduction.

constexpr int IN_F   = 256;
constexpr int OUT_F  = 256;
constexpr int BROWS  = 2048;
constexpr int BTILE  = 8;                 // batch rows per block
constexpr int ISPLIT = 8;                 // i-groups per block (one wave each)
constexpr int ICHUNK = IN_F / ISPLIT;     // 32 i per group
constexpr int OPAIRS = 64;                // o-pairs per block (= 128 o columns)

#define INV2PI 0.15915494309189535f

__global__ __launch_bounds__(OPAIRS * ISPLIT, 4) void ripple_kernel(
    const float* __restrict__ x,       // (BROWS, IN_F)
    const float* __restrict__ weight,  // (IN_F, OUT_F, 2)
    const float* __restrict__ bias,    // (IN_F+1, OUT_F)
    float* __restrict__ out)           // (BROWS, OUT_F)
{
    const int tx = threadIdx.x;           // 0..63: o-pair lane
    const int g  = threadIdx.y;           // 0..7: i-group (one wave)
    const int ob = blockIdx.x & 1;        // which o-half
    const int bb = blockIdx.x >> 1;       // row-block
    const int b0 = bb * BTILE;
    const int oc = ob * OPAIRS + tx;      // global o-pair index 0..127

    __shared__ __align__(16) float xs_t[BTILE * IN_F];  // 8 KB, xs_t[i*8+r] = x/(2pi)
    __shared__ float2 red[4][BTILE][OPAIRS];            // 16 KB reduction buffer

    // --- stage x-tile transposed + prescaled: 512 threads x float4 ---
    {
        const int t  = g * OPAIRS + tx;   // 0..511
        const int r  = t >> 6;            // row 0..7
        const int c4 = t & 63;            // float4 column
        const float4 v = ((const float4*)x)[(b0 + r) * (IN_F / 4) + c4];
        xs_t[(4 * c4 + 0) * BTILE + r] = v.x * INV2PI;
        xs_t[(4 * c4 + 1) * BTILE + r] = v.y * INV2PI;
        xs_t[(4 * c4 + 2) * BTILE + r] = v.z * INV2PI;
        xs_t[(4 * c4 + 3) * BTILE + r] = v.w * INV2PI;
    }
    __syncthreads();

    float acc0[BTILE], acc1[BTILE];
#pragma unroll
    for (int r = 0; r < BTILE; ++r) { acc0[r] = 0.0f; acc1[r] = 0.0f; }

    const float4* __restrict__ wq  = (const float4*)weight;  // (amp0,freq0,amp1,freq1)
    const float2* __restrict__ ph2 = (const float2*)bias;    // phase pairs

    const int i0 = g * ICHUNK;
#pragma unroll 4
    for (int ii = 0; ii < ICHUNK; ++ii) {
        const int i = i0 + ii;
        const float4 w = wq[i * (OUT_F / 2) + oc];           // 16B coalesced
        const float2 p = ph2[(i + 1) * (OUT_F / 2) + oc];    // 8B coalesced
        const float px = p.x * INV2PI;
        const float py = p.y * INV2PI;
        const float4 xa = *(const float4*)&xs_t[i * BTILE];      // rows 0..3
        const float4 xb = *(const float4*)&xs_t[i * BTILE + 4];  // rows 4..7
        const float xv[BTILE] = {xa.x, xa.y, xa.z, xa.w, xb.x, xb.y, xb.z, xb.w};
#pragma unroll
        for (int r = 0; r < BTILE; ++r) {
            acc0[r] += w.x * __builtin_amdgcn_sinf(fmaf(xv[r], w.y, px));
            acc1[r] += w.z * __builtin_amdgcn_sinf(fmaf(xv[r], w.w, py));
        }
    }

    // --- 3-step cross-wave tree reduction over the 8 i-groups ---
    if (g >= 4) {
#pragma unroll
        for (int r = 0; r < BTILE; ++r) red[g - 4][r][tx] = make_float2(acc0[r], acc1[r]);
    }
    __syncthreads();
    if (g < 4) {
#pragma unroll
        for (int r = 0; r < BTILE; ++r) { float2 t = red[g][r][tx]; acc0[r] += t.x; acc1[r] += t.y; }
    }
    __syncthreads();
    if (g == 2 || g == 3) {
#pragma unroll
        for (int r = 0; r < BTILE; ++r) red[g - 2][r][tx] = make_float2(acc0[r], acc1[r]);
    }
    __syncthreads();
    if (g < 2) {
#pragma unroll
        for (int r = 0; r < BTILE; ++r) { float2 t = red[g][r][tx]; acc0[r] += t.x; acc1[r] += t.y; }
    }
    __syncthreads();
    if (g == 1) {
#pragma unroll
        for (int r = 0; r < BTILE; ++r) red[0][r][tx] = make_float2(acc0[r], acc1[r]);
    }
    __syncthreads();
    if (g == 0) {
        const float2 bo = ph2[oc];   // bias row 0, this o-pair (unscaled)
#pragma unroll
        for (int r = 0; r < BTILE; ++r) {
            float2 t = red[0][r][tx];
            float2 v = make_float2(acc0[r] + t.x + bo.x, acc1[r] + t.y + bo.y);
            ((float2*)out)[(b0 + r) * (OUT_F / 2) + oc] = v;
        }
    }
}

extern "C" void kernel_launch(void* const* d_in, const int* in_sizes, int n_in,
                              void* d_out, int out_size, void* d_ws, size_t ws_size,
                              hipStream_t stream) {
    const float* x      = (const float*)d_in[0];
    const float* weight = (const float*)d_in[1];
    const float* bias   = (const float*)d_in[2];
    float* out          = (float*)d_out;

    dim3 grid((BROWS / BTILE) * 2);     // 512 blocks: 256 row-blocks x 2 o-halves
    dim3 block(OPAIRS, ISPLIT);         // 512 threads = 8 waves
    ripple_kernel<<<grid, block, 0, stream>>>(x, weight, bias, out);
}